// Round 4
// baseline (331.433 us; speedup 1.0000x reference)
//
#include <hip/hip_runtime.h>
#include <hip/hip_bf16.h>
#include <stdint.h>

// Conv 3x3 SAME, NHWC fp32 in/out, implicit GEMM via bf16 MFMA.
// M = B*H*W = 100352, N = COUT = 256, K = 9*256 = 2304.
// Round 8: LDS-bandwidth attack. Rounds 0-3 established the kernel is
// LDS-read-BW-bound (~90% of conflicted-b128 ceiling; MFMA floor 47 us of
// 153 us = the 34% MfmaUtil). Fix: remove B from LDS entirely -- prep
// writes weights in EXACT MFMA fragment order; each wave loads its B
// fragments global->VGPR (1024B coalesced per instruction, L2-resident).
// A path identical to proven round-4 (DMA + u=sl^rl permuted staging,
// xor-swizzled b128 reads), double-buffered, one __syncthreads per K-step.

#define IMG_B 32
#define IMG_H 56
#define IMG_W 56
#define CIN   256
#define COUT  256
#define KDIM  2304          // 3*3*256
#define M_TOT 100352
#define HW    (IMG_H * IMG_W)
#define PW    58            // padded width
#define PHW   (PW * PW)     // 3364 padded pixels per image
#define BK    64            // k-elems per tile
#define ITERS (KDIM / BK)   // 36
#define TILE_E (128 * BK)   // 8192 elems = 16 KB per A buffer
#define PAD_BLOCKS 13456    // IMG_B*PHW*CIN / 8 / 256
#define WT_BLOCKS  (KDIM * COUT / 256)   // 2304

typedef __bf16 bf16_t;
typedef bf16_t bf16x8 __attribute__((ext_vector_type(8)));
typedef float  f32x4  __attribute__((ext_vector_type(4)));
typedef float  f32x16 __attribute__((ext_vector_type(16)));

typedef const __attribute__((address_space(1))) void GV;
typedef __attribute__((address_space(3))) void LV;

__device__ __forceinline__ void async16(const bf16_t* g, bf16_t* l) {
    // LDS dest = wave-uniform(l) + laneid*16; 16B per lane
    __builtin_amdgcn_global_load_lds((GV*)g, (LV*)l, 16, 0, 0);
}

// ---------- fused prep: pad image to bf16 [B][58][58][C] + weights in fragment order ----------
// wt2 element index: ((t*8 + n)*4 + kk)*512 + lane*8 + e
//   t  = k-step 0..35, n = 32-col group 0..7, kk = 16-k slice 0..3
//   lane's 8 elems: co = n*32 + (lane&31), k = t*64 + kk*16 + (lane>>5)*8 + e
// => one global_load_dwordx4 per (t,n,kk) fragment is 1024B contiguous AND
//    delivers the exact 32x32x16 MFMA B-operand register layout.
__global__ void prep_fused(const float* __restrict__ in, const float* __restrict__ kern,
                           bf16_t* __restrict__ pimg, bf16_t* __restrict__ wt2) {
    if (blockIdx.x < PAD_BLOCKS) {
        const size_t e = ((size_t)blockIdx.x * 256 + threadIdx.x) * 8;
        const int pix = (int)(e >> 8);          // padded pixel index
        const int c0  = (int)(e & 255);
        const int b   = pix / PHW;
        const int r   = pix - b * PHW;
        const int py  = r / PW;
        const int px  = r - py * PW;
        bf16x8 v = {};                          // border default: zeros
        if (py >= 1 && py <= IMG_H && px >= 1 && px <= IMG_W) {
            const f32x4* s = (const f32x4*)(in +
                ((((size_t)b * IMG_H + (py - 1)) * IMG_W + (px - 1)) << 8) + c0);
            f32x4 a = s[0], bq = s[1];
            #pragma unroll
            for (int k = 0; k < 4; ++k) v[k] = (bf16_t)a[k];
            #pragma unroll
            for (int k = 0; k < 4; ++k) v[4 + k] = (bf16_t)bq[k];
        }
        *(bf16x8*)(pimg + e) = v;
    } else {
        const int idx = (blockIdx.x - PAD_BLOCKS) * 256 + threadIdx.x; // 0..589823
        const int e  = idx & 7;
        const int l  = (idx >> 3) & 63;
        const int kk = (idx >> 9) & 3;
        const int n  = (idx >> 11) & 7;
        const int t  = idx >> 14;
        const int co = n * 32 + (l & 31);
        const int k  = t * 64 + kk * 16 + (l >> 5) * 8 + e;
        wt2[idx] = (bf16_t)kern[k * COUT + co];
    }
}

// ---------- standalone weight prep (fallback path only, [co][k] layout) ----------
__global__ void prep_weights(const float* __restrict__ kern, bf16_t* __restrict__ wt) {
    int idx = blockIdx.x * 256 + threadIdx.x;
    int co  = idx / KDIM;
    int k   = idx - co * KDIM;
    wt[idx] = (bf16_t)kern[k * COUT + co];
}

// ---------- main conv: 128x128 tile, A in LDS (dbuf), B global->reg ----------

// stage A k-step (t1) into buffer (cb): 4 async16 per wave, 128B/row granule.
#define STAGE_A(t1, cb) do { \
    const int tap_  = (t1) >> 2; \
    const int kh_   = tap_ / 3; \
    const int kw_   = tap_ - kh_ * 3; \
    const int koff_ = ((kh_ * PW + kw_) << 8) + (((t1) & 3) << 6); \
    _Pragma("unroll") \
    for (int i_ = 0; i_ < 4; ++i_) \
        async16(asrc[i_] + koff_, alds[i_] + (cb) * TILE_E); \
} while (0)

// load B fragments for k-step (t1) into dst[2][4] (global, L2-resident)
#define LOADB(t1, dst) do { \
    const size_t tb_ = (size_t)(t1) * 16384; \
    _Pragma("unroll") \
    for (int h_ = 0; h_ < 2; ++h_) \
        _Pragma("unroll") \
        for (int kk_ = 0; kk_ < 4; ++kk_) \
            dst[h_][kk_] = *(const bf16x8*)(pB[h_] + tb_ + kk_ * 512); \
} while (0)

// One K-step on A-buffer (cur): entry sync drains loads aged ~1 step,
// stage A(t+1) into other buffer, read A frags, prefetch B(t+1), MFMA.
#define STEP(t, cur, bcur, bnxt) do { \
    __syncthreads(); \
    if ((t) + 1 < ITERS) STAGE_A((t) + 1, (cur) ^ 1); \
    bf16x8 af[2][4]; \
    _Pragma("unroll") \
    for (int kk = 0; kk < 4; ++kk) { \
        const int slot_ = ((kk * 2 + lh) ^ rx) * 8; \
        af[0][kk] = *(const bf16x8*)(&Al[cur][(wm * 64 + ln) * BK + slot_]); \
        af[1][kk] = *(const bf16x8*)(&Al[cur][(wm * 64 + 32 + ln) * BK + slot_]); \
    } \
    if ((t) + 1 < ITERS) LOADB((t) + 1, bnxt); \
    __builtin_amdgcn_s_setprio(1); \
    _Pragma("unroll") \
    for (int kk = 0; kk < 4; ++kk) { \
        acc[0][0] = __builtin_amdgcn_mfma_f32_32x32x16_bf16(af[0][kk], bcur[0][kk], acc[0][0], 0, 0, 0); \
        acc[0][1] = __builtin_amdgcn_mfma_f32_32x32x16_bf16(af[0][kk], bcur[1][kk], acc[0][1], 0, 0, 0); \
        acc[1][0] = __builtin_amdgcn_mfma_f32_32x32x16_bf16(af[1][kk], bcur[0][kk], acc[1][0], 0, 0, 0); \
        acc[1][1] = __builtin_amdgcn_mfma_f32_32x32x16_bf16(af[1][kk], bcur[1][kk], acc[1][1], 0, 0, 0); \
    } \
    __builtin_amdgcn_s_setprio(0); \
} while (0)

__global__ __launch_bounds__(256, 2)
void conv_mfma_p(const bf16_t* __restrict__ P, const bf16_t* __restrict__ wt2,
                 const float* __restrict__ bias, float* __restrict__ out)
{
    __shared__ bf16_t Al[2][TILE_E];   // 2 x 16 KB (A only; B never touches LDS)

    const int tid  = threadIdx.x;
    const int wave = tid >> 6;
    const int lane = tid & 63;

    // XCD-contiguous tile mapping: blocks on one XCD cover 196 contiguous tiles
    const int bid   = blockIdx.x;
    const int tile  = (bid & 7) * 196 + (bid >> 3);
    const int ntile = tile & 1;
    const int mtile = tile >> 1;

    // ---- A staging roles: per DMA issue, 8 rows x 8 segs of 16B per wave ----
    const int rl = lane >> 3;         // row within 8-row group
    const int sl = lane & 7;          // LDS slot within row
    const int u  = sl ^ rl;           // swizzle: slot sl holds source seg u = sl^(row&7)

    const bf16_t* asrc[4];
    bf16_t* alds[4];
    #pragma unroll
    for (int i = 0; i < 4; ++i) {
        const int row = wave * 32 + i * 8 + rl;     // tile row 0..127
        const int m   = mtile * 128 + row;
        const int bb  = m / HW;
        const int rem = m - bb * HW;
        const int yy  = rem / IMG_W;
        const int xx  = rem - yy * IMG_W;
        asrc[i] = P + (((size_t)bb * PHW + yy * PW + xx) << 8) + u * 8;
        alds[i] = &Al[0][(wave * 32 + i * 8) * BK];  // wave-uniform bases (buf 0)
    }

    // ---- compute roles: wave (wm,wn) owns 64x64; 2x2 of 32x32 MFMA tiles ----
    const int wm = wave & 1;
    const int wn = wave >> 1;
    const int ln = lane & 31;
    const int lh = lane >> 5;
    const int rx = ln & 7;            // row&7 for swizzled read

    // B fragment pointers: group gn = ntile*4 + 2*wn + h
    const bf16_t* pB[2];
    #pragma unroll
    for (int h = 0; h < 2; ++h)
        pB[h] = wt2 + (size_t)(ntile * 4 + 2 * wn + h) * 2048 + lane * 8;

    f32x16 acc[2][2] = {};
    bf16x8 bf0[2][4], bf1[2][4];

    // prologue: stage A(0), load B(0)
    STAGE_A(0, 0);
    LOADB(0, bf0);

    #pragma unroll 1
    for (int t2 = 0; t2 < ITERS / 2; ++t2) {
        STEP(t2 * 2,     0, bf0, bf1);
        STEP(t2 * 2 + 1, 1, bf1, bf0);
    }

    // ---- epilogue: 32x32 C/D layout col=lane&31, row=(reg&3)+8*(reg>>2)+4*lh ----
    const int mbase  = mtile * 128 + wm * 64;
    const int cobase = ntile * 128 + wn * 64;
    float bv[2];
    bv[0] = bias[cobase + ln];
    bv[1] = bias[cobase + 32 + ln];

    #pragma unroll
    for (int g = 0; g < 2; ++g) {
        #pragma unroll
        for (int reg = 0; reg < 16; ++reg) {
            const int mm = mbase + g * 32 + (reg & 3) + 8 * (reg >> 2) + 4 * lh;
            float* op = out + (size_t)mm * COUT + cobase + ln;
            op[0]  = acc[g][0][reg] + bv[0];
            op[32] = acc[g][1][reg] + bv[1];
        }
    }
}

// ---------- fallback conv (fp32 staging, round-1 validated) ----------
#define ASTR 40
#define BSTR 40
__global__ __launch_bounds__(256)
void conv_mfma(const float* __restrict__ in, const bf16_t* __restrict__ wt,
               const float* __restrict__ bias, float* __restrict__ out)
{
    __shared__ bf16_t Alf[128 * ASTR];
    __shared__ bf16_t Blf[128 * BSTR];

    const int tid   = threadIdx.x;
    const int ntile = blockIdx.x & 1;
    const int mtile = blockIdx.x >> 1;

    const int arow = tid >> 1;
    const int aseg = tid & 1;
    const int m    = mtile * 128 + arow;
    const int bb   = m / HW;
    const int rem  = m - bb * HW;
    const int yy   = rem / IMG_W;
    const int xx   = rem - yy * IMG_W;

    const bf16_t* wt_row = wt + (size_t)(ntile * 128 + arow) * KDIM + aseg * 16;

    const int wave = tid >> 6;
    const int lane = tid & 63;
    const int wm   = wave & 1;
    const int wn   = wave >> 1;
    const int lrow = lane & 15;
    const int q    = lane >> 4;

    f32x4 acc[4][4] = {};

    #pragma unroll 1
    for (int it = 0; it < 72; ++it) {
        const int tap = it >> 3;
        const int kh  = tap / 3;
        const int kw  = tap - kh * 3;
        const int ci0 = (it & 7) << 5;

        const int iy = yy + kh - 1;
        const int ix = xx + kw - 1;
        const bool valid = ((unsigned)iy < IMG_H) && ((unsigned)ix < IMG_W);

        f32x4 va[4] = {};
        if (valid) {
            const f32x4* src = (const f32x4*)(in +
                ((((size_t)bb * IMG_H + iy) * IMG_W + ix) * CIN + ci0 + aseg * 16));
            va[0] = src[0]; va[1] = src[1]; va[2] = src[2]; va[3] = src[3];
        }
        const uint4 wb0 = *(const uint4*)(wt_row + it * 32);
        const uint4 wb1 = *(const uint4*)(wt_row + it * 32 + 8);

        __syncthreads();

        bf16x8 pa0, pa1;
        #pragma unroll
        for (int e = 0; e < 8; ++e) pa0[e] = (bf16_t)va[e >> 2][e & 3];
        #pragma unroll
        for (int e = 0; e < 8; ++e) pa1[e] = (bf16_t)va[2 + (e >> 2)][e & 3];
        *(bf16x8*)(&Alf[arow * ASTR + aseg * 16])     = pa0;
        *(bf16x8*)(&Alf[arow * ASTR + aseg * 16 + 8]) = pa1;
        *(uint4*)(&Blf[arow * BSTR + aseg * 16])      = wb0;
        *(uint4*)(&Blf[arow * BSTR + aseg * 16 + 8])  = wb1;

        __syncthreads();

        bf16x8 af[4], bf[4];
        #pragma unroll
        for (int i = 0; i < 4; ++i)
            af[i] = *(const bf16x8*)(&Alf[(wm * 64 + i * 16 + lrow) * ASTR + q * 8]);
        #pragma unroll
        for (int j = 0; j < 4; ++j)
            bf[j] = *(const bf16x8*)(&Blf[(wn * 64 + j * 16 + lrow) * BSTR + q * 8]);

        #pragma unroll
        for (int i = 0; i < 4; ++i)
            #pragma unroll
            for (int j = 0; j < 4; ++j)
                acc[i][j] = __builtin_amdgcn_mfma_f32_16x16x32_bf16(af[i], bf[j], acc[i][j], 0, 0, 0);
    }

    const int co_base = ntile * 128 + wn * 64;
    float bv[4];
    #pragma unroll
    for (int j = 0; j < 4; ++j) bv[j] = bias[co_base + j * 16 + lrow];

    const int mrow_base = mtile * 128 + wm * 64;
    #pragma unroll
    for (int i = 0; i < 4; ++i) {
        #pragma unroll
        for (int rr = 0; rr < 4; ++rr) {
            const int mm = mrow_base + i * 16 + q * 4 + rr;
            float* op = out + (size_t)mm * COUT + co_base;
            #pragma unroll
            for (int j = 0; j < 4; ++j)
                op[j * 16 + lrow] = acc[i][j][rr] + bv[j];
        }
    }
}

extern "C" void kernel_launch(void* const* d_in, const int* in_sizes, int n_in,
                              void* d_out, int out_size, void* d_ws, size_t ws_size,
                              hipStream_t stream) {
    const float* inputs = (const float*)d_in[0];
    const float* kernel = (const float*)d_in[1];
    const float* bias   = (const float*)d_in[2];
    float*       outp   = (float*)d_out;

    const size_t p_elems = (size_t)IMG_B * PHW * CIN;               // 27,557,888
    const size_t p_bytes = p_elems * sizeof(bf16_t);                // 55.1 MB
    const size_t w_bytes = (size_t)KDIM * COUT * sizeof(bf16_t);    // 1.18 MB

    if (ws_size >= p_bytes + w_bytes) {
        bf16_t* pimg = (bf16_t*)d_ws;
        bf16_t* wt2  = (bf16_t*)((char*)d_ws + p_bytes);
        prep_fused<<<PAD_BLOCKS + WT_BLOCKS, 256, 0, stream>>>(inputs, kernel, pimg, wt2);
        conv_mfma_p<<<(M_TOT / 128) * 2, 256, 0, stream>>>(pimg, wt2, bias, outp);
    } else {
        bf16_t* wt = (bf16_t*)d_ws;
        prep_weights<<<WT_BLOCKS, 256, 0, stream>>>(kernel, wt);
        conv_mfma<<<(M_TOT / 128) * 2, 256, 0, stream>>>(inputs, wt, bias, outp);
    }
}

// Round 6
// 325.799 us; speedup vs baseline: 1.0173x; 1.0173x over previous
//
#include <hip/hip_runtime.h>
#include <hip/hip_bf16.h>
#include <stdint.h>

// Conv 3x3 SAME, NHWC fp32 in/out, implicit GEMM via bf16 MFMA.
// M = B*H*W = 100352, N = COUT = 256, K = 9*256 = 2304.
// Round 10 (= round-9 theory, compile-fixed): bigger wave tile.
// r4/r7/r8 triangulated the ceiling to per-MFMA overhead (LDS reads +
// VMEM inst + staged bytes), not any single pipe. Block 128x256 (BN =
// full COUT), wave tile 64x128: 0.75 LDS-reads/MFMA (was 1.0), 0.19
// VMEM-inst/MFMA (was 0.5), 1.5KB staged/MFMA (was 2.0). A single-
// buffered (16KB, r4-proven read->sync->stage order); B double-buffered
// (2x32KB) so bf frags stream per-kk after staging is issued.
// LDS 80KB -> 2 blocks/CU. Grid 784 = 8*98, bijective XCD swizzle.

#define IMG_B 32
#define IMG_H 56
#define IMG_W 56
#define CIN   256
#define COUT  256
#define KDIM  2304          // 3*3*256
#define M_TOT 100352
#define HW    (IMG_H * IMG_W)
#define PW    58            // padded width
#define PHW   (PW * PW)     // 3364 padded pixels per image
#define BK    64            // k-elems per tile
#define ITERS (KDIM / BK)   // 36
#define PAD_BLOCKS 13456    // IMG_B*PHW*CIN / 8 / 256
#define WT_BLOCKS  (KDIM * COUT / 256)   // 2304

typedef __bf16 bf16_t;
typedef bf16_t bf16x8 __attribute__((ext_vector_type(8)));
typedef float  f32x4  __attribute__((ext_vector_type(4)));
typedef float  f32x16 __attribute__((ext_vector_type(16)));

typedef const __attribute__((address_space(1))) void GV;
typedef __attribute__((address_space(3))) void LV;

__device__ __forceinline__ void async16(const bf16_t* g, bf16_t* l) {
    // LDS dest = wave-uniform(l) + laneid*16; 16B per lane
    __builtin_amdgcn_global_load_lds((GV*)g, (LV*)l, 16, 0, 0);
}

// ---------- fused prep: pad image to bf16 [B][58][58][C] + weights -> Wt[co][k] ----------
__global__ void prep_fused(const float* __restrict__ in, const float* __restrict__ kern,
                           bf16_t* __restrict__ pimg, bf16_t* __restrict__ wt) {
    if (blockIdx.x < PAD_BLOCKS) {
        const size_t e = ((size_t)blockIdx.x * 256 + threadIdx.x) * 8;
        const int pix = (int)(e >> 8);          // padded pixel index
        const int c0  = (int)(e & 255);
        const int b   = pix / PHW;
        const int r   = pix - b * PHW;
        const int py  = r / PW;
        const int px  = r - py * PW;
        bf16x8 v = {};                          // border default: zeros
        if (py >= 1 && py <= IMG_H && px >= 1 && px <= IMG_W) {
            const f32x4* s = (const f32x4*)(in +
                ((((size_t)b * IMG_H + (py - 1)) * IMG_W + (px - 1)) << 8) + c0);
            f32x4 a = s[0], bq = s[1];
            #pragma unroll
            for (int k = 0; k < 4; ++k) v[k] = (bf16_t)a[k];
            #pragma unroll
            for (int k = 0; k < 4; ++k) v[4 + k] = (bf16_t)bq[k];
        }
        *(bf16x8*)(pimg + e) = v;
    } else {
        const int idx = (blockIdx.x - PAD_BLOCKS) * 256 + threadIdx.x;
        const int co  = idx / KDIM;
        const int k   = idx - co * KDIM;
        wt[idx] = (bf16_t)kern[k * COUT + co];  // coalesced bf16 writes
    }
}

// ---------- standalone weight prep (fallback path only) ----------
__global__ void prep_weights(const float* __restrict__ kern, bf16_t* __restrict__ wt) {
    int idx = blockIdx.x * 256 + threadIdx.x;
    int co  = idx / KDIM;
    int k   = idx - co * KDIM;
    wt[idx] = (bf16_t)kern[k * COUT + co];
}

// ---------- main conv: 128x256 tile, wave tile 64x128, A single / B dbuf ----------

// stage A k-step (t1): 4 async16 per wave, 128B/row granule, u=sl^rl permuted.
#define STAGE_A(t1) do { \
    const int tap_  = (t1) >> 2; \
    const int kh_   = tap_ / 3; \
    const int kw_   = tap_ - kh_ * 3; \
    const int koff_ = ((kh_ * PW + kw_) << 8) + (((t1) & 3) << 6); \
    _Pragma("unroll") \
    for (int i_ = 0; i_ < 4; ++i_) \
        async16(asrc[i_] + koff_, alds[i_]); \
} while (0)

// stage B k-step (t1) into buffer (nb): 8 async16 per wave (rows wave*64..+63).
#define STAGE_B(t1, nb) do { \
    const int woff_ = (t1) * BK; \
    _Pragma("unroll") \
    for (int i_ = 0; i_ < 8; ++i_) \
        async16(bsrc0 + (size_t)i_ * (8 * KDIM) + woff_, \
                &Bl[(nb)][(wave * 64 + i_ * 8) * BK]); \
} while (0)

__global__ __launch_bounds__(256, 2)
void conv_wide(const bf16_t* __restrict__ P, const bf16_t* __restrict__ wt,
               const float* __restrict__ bias, float* __restrict__ out)
{
    __shared__ bf16_t Al[128 * BK];        // 16 KB, single-buffered
    __shared__ bf16_t Bl[2][256 * BK];     // 2 x 32 KB (80 KB total -> 2 blocks/CU)

    const int tid  = threadIdx.x;
    const int wave = tid >> 6;
    const int lane = tid & 63;

    const int bid   = blockIdx.x;
    const int mtile = (bid & 7) * 98 + (bid >> 3);   // 784 = 8*98, bijective

    // ---- staging roles: per DMA issue, 8 rows x 8 segs of 16B per wave ----
    const int rl = lane >> 3;         // row within 8-row group
    const int sl = lane & 7;          // LDS slot within row
    const int u  = sl ^ rl;           // swizzle: slot sl holds source seg u = sl^(row&7)

    const bf16_t* asrc[4];
    bf16_t* alds[4];
    #pragma unroll
    for (int i = 0; i < 4; ++i) {
        const int row = wave * 32 + i * 8 + rl;     // tile row 0..127
        const int m   = mtile * 128 + row;
        const int bb  = m / HW;
        const int rem = m - bb * HW;
        const int yy  = rem / IMG_W;
        const int xx  = rem - yy * IMG_W;
        asrc[i] = P + (((size_t)bb * PHW + yy * PW + xx) << 8) + u * 8;
        alds[i] = &Al[(wave * 32 + i * 8) * BK];    // wave-uniform bases
    }
    // B staging: wave stages co rows wave*64 + i*8 + rl, i = 0..7
    const bf16_t* bsrc0 = wt + (size_t)(wave * 64 + rl) * KDIM + u * 8;

    // ---- compute roles: wave (wm,wn) owns 64x128; 2x4 of 32x32 MFMA tiles ----
    const int wm = wave & 1;
    const int wn = wave >> 1;         // 0..1
    const int ln = lane & 31;
    const int lh = lane >> 5;
    const int rx = ln & 7;            // row&7 for swizzled read

    f32x16 acc[2][4] = {};

    // prologue: stage iter 0
    STAGE_A(0);
    STAGE_B(0, 0);

    #pragma unroll 1
    for (int it = 0; it < ITERS; ++it) {
        const int bc = it & 1;
        __syncthreads();                       // DMA for iter `it` landed

        bf16x8 af[2][4];
        #pragma unroll
        for (int kk = 0; kk < 4; ++kk) {
            const int slot = ((kk * 2 + lh) ^ rx) * 8;
            af[0][kk] = *(const bf16x8*)(&Al[(wm * 64 + ln) * BK + slot]);
            af[1][kk] = *(const bf16x8*)(&Al[(wm * 64 + 32 + ln) * BK + slot]);
        }

        __syncthreads();                       // A reads done; Al reusable

        if (it + 1 < ITERS) {
            STAGE_A(it + 1);
            STAGE_B(it + 1, bc ^ 1);
        }

        #pragma unroll
        for (int kk = 0; kk < 4; ++kk) {
            const int slot = ((kk * 2 + lh) ^ rx) * 8;
            const bf16x8 bf0 = *(const bf16x8*)(&Bl[bc][(wn * 128 + ln) * BK + slot]);
            const bf16x8 bf1 = *(const bf16x8*)(&Bl[bc][(wn * 128 + 32 + ln) * BK + slot]);
            const bf16x8 bf2 = *(const bf16x8*)(&Bl[bc][(wn * 128 + 64 + ln) * BK + slot]);
            const bf16x8 bf3 = *(const bf16x8*)(&Bl[bc][(wn * 128 + 96 + ln) * BK + slot]);
            __builtin_amdgcn_s_setprio(1);
            acc[0][0] = __builtin_amdgcn_mfma_f32_32x32x16_bf16(af[0][kk], bf0, acc[0][0], 0, 0, 0);
            acc[0][1] = __builtin_amdgcn_mfma_f32_32x32x16_bf16(af[0][kk], bf1, acc[0][1], 0, 0, 0);
            acc[0][2] = __builtin_amdgcn_mfma_f32_32x32x16_bf16(af[0][kk], bf2, acc[0][2], 0, 0, 0);
            acc[0][3] = __builtin_amdgcn_mfma_f32_32x32x16_bf16(af[0][kk], bf3, acc[0][3], 0, 0, 0);
            acc[1][0] = __builtin_amdgcn_mfma_f32_32x32x16_bf16(af[1][kk], bf0, acc[1][0], 0, 0, 0);
            acc[1][1] = __builtin_amdgcn_mfma_f32_32x32x16_bf16(af[1][kk], bf1, acc[1][1], 0, 0, 0);
            acc[1][2] = __builtin_amdgcn_mfma_f32_32x32x16_bf16(af[1][kk], bf2, acc[1][2], 0, 0, 0);
            acc[1][3] = __builtin_amdgcn_mfma_f32_32x32x16_bf16(af[1][kk], bf3, acc[1][3], 0, 0, 0);
            __builtin_amdgcn_s_setprio(0);
        }
    }

    // ---- epilogue: 32x32 C/D layout col=lane&31, row=(reg&3)+8*(reg>>2)+4*lh ----
    const int mbase  = mtile * 128 + wm * 64;
    const int cobase = wn * 128;
    float bv[4];
    #pragma unroll
    for (int j = 0; j < 4; ++j) bv[j] = bias[cobase + j * 32 + ln];

    #pragma unroll
    for (int g = 0; g < 2; ++g) {
        #pragma unroll
        for (int reg = 0; reg < 16; ++reg) {
            const int mm = mbase + g * 32 + (reg & 3) + 8 * (reg >> 2) + 4 * lh;
            float* op = out + (size_t)mm * COUT + cobase + ln;
            #pragma unroll
            for (int j = 0; j < 4; ++j)
                op[j * 32] = acc[g][j][reg] + bv[j];
        }
    }
}

// ---------- fallback conv (fp32 staging, round-1 validated) ----------
#define ASTR 40
#define BSTR 40
__global__ __launch_bounds__(256)
void conv_mfma(const float* __restrict__ in, const bf16_t* __restrict__ wt,
               const float* __restrict__ bias, float* __restrict__ out)
{
    __shared__ bf16_t Alf[128 * ASTR];
    __shared__ bf16_t Blf[128 * BSTR];

    const int tid   = threadIdx.x;
    const int ntile = blockIdx.x & 1;
    const int mtile = blockIdx.x >> 1;

    const int arow = tid >> 1;
    const int aseg = tid & 1;
    const int m    = mtile * 128 + arow;
    const int bb   = m / HW;
    const int rem  = m - bb * HW;
    const int yy   = rem / IMG_W;
    const int xx   = rem - yy * IMG_W;

    const bf16_t* wt_row = wt + (size_t)(ntile * 128 + arow) * KDIM + aseg * 16;

    const int wave = tid >> 6;
    const int lane = tid & 63;
    const int wm   = wave & 1;
    const int wn   = wave >> 1;
    const int lrow = lane & 15;
    const int q    = lane >> 4;

    f32x4 acc[4][4] = {};

    #pragma unroll 1
    for (int it = 0; it < 72; ++it) {
        const int tap = it >> 3;
        const int kh  = tap / 3;
        const int kw  = tap - kh * 3;
        const int ci0 = (it & 7) << 5;

        const int iy = yy + kh - 1;
        const int ix = xx + kw - 1;
        const bool valid = ((unsigned)iy < IMG_H) && ((unsigned)ix < IMG_W);

        f32x4 va[4] = {};
        if (valid) {
            const f32x4* src = (const f32x4*)(in +
                ((((size_t)bb * IMG_H + iy) * IMG_W + ix) * CIN + ci0 + aseg * 16));
            va[0] = src[0]; va[1] = src[1]; va[2] = src[2]; va[3] = src[3];
        }
        const uint4 wb0 = *(const uint4*)(wt_row + it * 32);
        const uint4 wb1 = *(const uint4*)(wt_row + it * 32 + 8);

        __syncthreads();

        bf16x8 pa0, pa1;
        #pragma unroll
        for (int e = 0; e < 8; ++e) pa0[e] = (bf16_t)va[e >> 2][e & 3];
        #pragma unroll
        for (int e = 0; e < 8; ++e) pa1[e] = (bf16_t)va[2 + (e >> 2)][e & 3];
        *(bf16x8*)(&Alf[arow * ASTR + aseg * 16])     = pa0;
        *(bf16x8*)(&Alf[arow * ASTR + aseg * 16 + 8]) = pa1;
        *(uint4*)(&Blf[arow * BSTR + aseg * 16])      = wb0;
        *(uint4*)(&Blf[arow * BSTR + aseg * 16 + 8])  = wb1;

        __syncthreads();

        bf16x8 af[4], bf[4];
        #pragma unroll
        for (int i = 0; i < 4; ++i)
            af[i] = *(const bf16x8*)(&Alf[(wm * 64 + i * 16 + lrow) * ASTR + q * 8]);
        #pragma unroll
        for (int j = 0; j < 4; ++j)
            bf[j] = *(const bf16x8*)(&Blf[(wn * 64 + j * 16 + lrow) * BSTR + q * 8]);

        #pragma unroll
        for (int i = 0; i < 4; ++i)
            #pragma unroll
            for (int j = 0; j < 4; ++j)
                acc[i][j] = __builtin_amdgcn_mfma_f32_16x16x32_bf16(af[i], bf[j], acc[i][j], 0, 0, 0);
    }

    const int co_base = ntile * 128 + wn * 64;
    float bv[4];
    #pragma unroll
    for (int j = 0; j < 4; ++j) bv[j] = bias[co_base + j * 16 + lrow];

    const int mrow_base = mtile * 128 + wm * 64;
    #pragma unroll
    for (int i = 0; i < 4; ++i) {
        #pragma unroll
        for (int rr = 0; rr < 4; ++rr) {
            const int mm = mrow_base + i * 16 + q * 4 + rr;
            float* op = out + (size_t)mm * COUT + co_base;
            #pragma unroll
            for (int j = 0; j < 4; ++j)
                op[j * 16 + lrow] = acc[i][j][rr] + bv[j];
        }
    }
}

extern "C" void kernel_launch(void* const* d_in, const int* in_sizes, int n_in,
                              void* d_out, int out_size, void* d_ws, size_t ws_size,
                              hipStream_t stream) {
    const float* inputs = (const float*)d_in[0];
    const float* kernel = (const float*)d_in[1];
    const float* bias   = (const float*)d_in[2];
    float*       outp   = (float*)d_out;

    const size_t p_elems = (size_t)IMG_B * PHW * CIN;               // 27,557,888
    const size_t p_bytes = p_elems * sizeof(bf16_t);                // 55.1 MB
    const size_t w_bytes = (size_t)KDIM * COUT * sizeof(bf16_t);    // 1.18 MB

    if (ws_size >= p_bytes + w_bytes) {
        bf16_t* pimg = (bf16_t*)d_ws;
        bf16_t* wt   = (bf16_t*)((char*)d_ws + p_bytes);
        prep_fused<<<PAD_BLOCKS + WT_BLOCKS, 256, 0, stream>>>(inputs, kernel, pimg, wt);
        conv_wide<<<M_TOT / 128, 256, 0, stream>>>(pimg, wt, bias, outp);
    } else {
        bf16_t* wt = (bf16_t*)d_ws;
        prep_weights<<<WT_BLOCKS, 256, 0, stream>>>(kernel, wt);
        conv_mfma<<<(M_TOT / 128) * 2, 256, 0, stream>>>(inputs, wt, bias, outp);
    }
}

// Round 7
// 314.722 us; speedup vs baseline: 1.0531x; 1.0352x over previous
//
#include <hip/hip_runtime.h>
#include <hip/hip_bf16.h>
#include <stdint.h>

// Conv 3x3 SAME, NHWC fp32 in/out, implicit GEMM via bf16 MFMA.
// M = B*H*W = 100352, N = COUT = 256, K = 9*256 = 2304.
// Round 11: conv reverted to the proven round-4 kernel (152 us, best
// measured). Prep restructured for diagnosis + speed: the total-minus-conv
// residual has been a constant ~158 us across all six rounds; prep's
// traffic floor is ~30 us. Split prep into three named, branch-free
// streaming kernels so rocprof attributes the residual:
//   prep_interior: fp32->bf16 copy of all interior pixels (no divisions
//                  in the hot path, coalesced 32B reads / 16B writes)
//   prep_border:   zeros the 3.7 MB of border pixels only
//   prep_weights:  HWIO -> [co][k] bf16 transpose (2.4 MB, L2-resident)

#define IMG_B 32
#define IMG_H 56
#define IMG_W 56
#define CIN   256
#define COUT  256
#define KDIM  2304          // 3*3*256
#define M_TOT 100352
#define HW    (IMG_H * IMG_W)
#define PW    58            // padded width
#define PHW   (PW * PW)     // 3364 padded pixels per image
#define BK    64            // k-elems per tile
#define ITERS (KDIM / BK)   // 36
#define WT_BLOCKS  (KDIM * COUT / 256)       // 2304
#define INT_BLOCKS (IMG_B * IMG_H * 7)       // 12544: one block = 1/7 of a row
#define BORDER_PIX 228                       // per image: 58+58+56+56
#define BORDER_THREADS (IMG_B * BORDER_PIX * 32)   // 233472 = 912 * 256
#define BORDER_BLOCKS (BORDER_THREADS / 256)       // 912

typedef __bf16 bf16_t;
typedef bf16_t bf16x8 __attribute__((ext_vector_type(8)));
typedef float  f32x4  __attribute__((ext_vector_type(4)));
typedef float  f32x16 __attribute__((ext_vector_type(16)));

typedef const __attribute__((address_space(1))) void GV;
typedef __attribute__((address_space(3))) void LV;

__device__ __forceinline__ void async16(const bf16_t* g, bf16_t* l) {
    // LDS dest = wave-uniform(l) + laneid*16; 16B per lane
    __builtin_amdgcn_global_load_lds((GV*)g, (LV*)l, 16, 0, 0);
}

// ---------- prep 1: interior copy fp32 NHWC -> bf16 padded [B][58][58][C] ----------
// One block = 2048 elems of one image row (row = 56 px * 256 ch = 14336 = 7 blocks).
// Branch-free vector copy; src and dst both contiguous within the row.
__global__ void prep_interior(const float* __restrict__ in, bf16_t* __restrict__ out) {
    const int bid   = blockIdx.x;
    const int chunk = bid % 7;
    const int rid   = bid / 7;            // 0 .. B*H-1
    const int b     = rid / IMG_H;
    const int y     = rid - b * IMG_H;
    const int e     = chunk * 2048 + threadIdx.x * 8;   // elem within row [0,14336)

    const float* s = in + ((((size_t)b * IMG_H + y) * IMG_W) << 8) + e;
    bf16_t*      d = out + (((size_t)b * PHW + (y + 1) * PW + 1) << 8) + e;

    const f32x4 a = *(const f32x4*)s;
    const f32x4 c = *(const f32x4*)(s + 4);
    bf16x8 v;
    #pragma unroll
    for (int k = 0; k < 4; ++k) { v[k] = (bf16_t)a[k]; v[4 + k] = (bf16_t)c[k]; }
    *(bf16x8*)d = v;
}

// ---------- prep 2: zero border pixels of the padded image ----------
__global__ void prep_border(bf16_t* __restrict__ out) {
    const int idx = blockIdx.x * 256 + threadIdx.x;     // < BORDER_THREADS exactly
    const int p   = idx >> 5;             // border pixel id
    const int c0  = (idx & 31) << 3;
    const int b   = p / BORDER_PIX;
    const int j   = p - b * BORDER_PIX;
    int py, px;
    if      (j < 58)  { py = 0;            px = j;       }
    else if (j < 116) { py = 57;           px = j - 58;  }
    else if (j < 172) { py = j - 116 + 1;  px = 0;       }
    else              { py = j - 172 + 1;  px = 57;      }
    bf16x8 z = {};
    *(bf16x8*)(out + (((size_t)b * PHW + py * PW + px) << 8) + c0) = z;
}

// ---------- prep 3: HWIO f32 kernel[k][co] -> Wt bf16 [co][k] ----------
__global__ void prep_weights(const float* __restrict__ kern, bf16_t* __restrict__ wt) {
    int idx = blockIdx.x * 256 + threadIdx.x;          // 0 .. 2304*256-1
    int co  = idx / KDIM;
    int k   = idx - co * KDIM;
    wt[idx] = (bf16_t)kern[k * COUT + co];             // coalesced bf16 writes
}

// ---------- main conv: 128x128 tile, BK=64, 32x32x16 MFMA, swizzled LDS ----------
// (exact round-4 kernel: proven 152 us, MfmaUtil 34)
__global__ __launch_bounds__(256)
void conv_mfma_p(const bf16_t* __restrict__ P, const bf16_t* __restrict__ wt,
                 const float* __restrict__ bias, float* __restrict__ out)
{
    __shared__ bf16_t Al[128 * BK];   // 16 KB, row-major [row][k], seg-swizzled
    __shared__ bf16_t Bl[128 * BK];   // 16 KB

    const int tid  = threadIdx.x;
    const int wave = tid >> 6;
    const int lane = tid & 63;

    // XCD-contiguous tile mapping: blocks on one XCD cover 196 contiguous tiles
    const int bid   = blockIdx.x;
    const int tile  = (bid & 7) * 196 + (bid >> 3);
    const int ntile = tile & 1;
    const int mtile = tile >> 1;

    // ---- staging roles: per DMA issue, 8 rows x 8 segs of 16B per wave ----
    const int rl = lane >> 3;         // row within 8-row group
    const int sl = lane & 7;          // LDS slot within row
    const int u  = sl ^ rl;           // swizzle: slot sl holds source seg u = sl^(row&7)

    const bf16_t* asrc[4];
    const bf16_t* bsrc[4];
    bf16_t* alds[4];
    bf16_t* blds[4];
    #pragma unroll
    for (int i = 0; i < 4; ++i) {
        const int row = wave * 32 + i * 8 + rl;     // tile row 0..127
        const int m   = mtile * 128 + row;
        const int bb  = m / HW;
        const int rem = m - bb * HW;
        const int yy  = rem / IMG_W;
        const int xx  = rem - yy * IMG_W;
        asrc[i] = P + (((size_t)bb * PHW + yy * PW + xx) << 8) + u * 8;
        const int co = ntile * 128 + row;
        bsrc[i] = wt + (size_t)co * KDIM + u * 8;
        alds[i] = &Al[(wave * 32 + i * 8) * BK];    // wave-uniform bases
        blds[i] = &Bl[(wave * 32 + i * 8) * BK];
    }

    // ---- compute roles: wave (wm,wn) owns 64x64; 2x2 of 32x32 MFMA tiles ----
    const int wm = wave & 1;
    const int wn = wave >> 1;
    const int ln = lane & 31;
    const int lh = lane >> 5;
    const int rx = ln & 7;            // row&7 for swizzled read

    f32x16 acc[2][2] = {};

    // prologue: stage iter 0 (tap 0 => koff 0)
    #pragma unroll
    for (int i = 0; i < 4; ++i) {
        async16(asrc[i], alds[i]);
        async16(bsrc[i], blds[i]);
    }

    #pragma unroll 1
    for (int it = 0; it < ITERS; ++it) {
        __syncthreads();   // DMA for iter `it` complete in LDS

        // fragment reads: 16 x ds_read_b128, conflict-managed via swizzle
        bf16x8 af[2][4], bf[2][4];
        #pragma unroll
        for (int kk = 0; kk < 4; ++kk) {
            const int slot = ((kk * 2 + lh) ^ rx) * 8;
            #pragma unroll
            for (int g = 0; g < 2; ++g) {
                af[g][kk] = *(const bf16x8*)(&Al[(wm * 64 + g * 32 + ln) * BK + slot]);
                bf[g][kk] = *(const bf16x8*)(&Bl[(wn * 64 + g * 32 + ln) * BK + slot]);
            }
        }

        __syncthreads();   // reads done; LDS free for next iter's DMA

        if (it + 1 < ITERS) {      // issue next DMA BEFORE the MFMA block
            const int itn  = it + 1;
            const int tap  = itn >> 2;
            const int kh   = tap / 3;
            const int kw   = tap - kh * 3;
            const int koff = ((kh * PW + kw) << 8) + ((itn & 3) << 6);
            const int woff = itn * BK;
            #pragma unroll
            for (int i = 0; i < 4; ++i) {
                async16(asrc[i] + koff, alds[i]);
                async16(bsrc[i] + woff, blds[i]);
            }
        }

        // MFMA: 16 x 32x32x16 (DMA flight overlaps this)
        #pragma unroll
        for (int kk = 0; kk < 4; ++kk)
            #pragma unroll
            for (int g = 0; g < 2; ++g)
                #pragma unroll
                for (int h = 0; h < 2; ++h)
                    acc[g][h] = __builtin_amdgcn_mfma_f32_32x32x16_bf16(
                        af[g][kk], bf[h][kk], acc[g][h], 0, 0, 0);
    }

    // ---- epilogue: 32x32 C/D layout col=lane&31, row=(reg&3)+8*(reg>>2)+4*lh ----
    const int mbase  = mtile * 128 + wm * 64;
    const int cobase = ntile * 128 + wn * 64;
    float bv[2];
    #pragma unroll
    for (int h = 0; h < 2; ++h) bv[h] = bias[cobase + h * 32 + ln];

    #pragma unroll
    for (int g = 0; g < 2; ++g) {
        #pragma unroll
        for (int reg = 0; reg < 16; ++reg) {
            const int mm = mbase + g * 32 + (reg & 3) + 8 * (reg >> 2) + 4 * lh;
            float* op = out + (size_t)mm * COUT + cobase + ln;
            op[0]  = acc[g][0][reg] + bv[0];
            op[32] = acc[g][1][reg] + bv[1];
        }
    }
}

// ---------- fallback conv (fp32 staging, round-1 validated) ----------
#define ASTR 40
#define BSTR 40
__global__ __launch_bounds__(256)
void conv_mfma(const float* __restrict__ in, const bf16_t* __restrict__ wt,
               const float* __restrict__ bias, float* __restrict__ out)
{
    __shared__ bf16_t Alf[128 * ASTR];
    __shared__ bf16_t Blf[128 * BSTR];

    const int tid   = threadIdx.x;
    const int ntile = blockIdx.x & 1;
    const int mtile = blockIdx.x >> 1;

    const int arow = tid >> 1;
    const int aseg = tid & 1;
    const int m    = mtile * 128 + arow;
    const int bb   = m / HW;
    const int rem  = m - bb * HW;
    const int yy   = rem / IMG_W;
    const int xx   = rem - yy * IMG_W;

    const bf16_t* wt_row = wt + (size_t)(ntile * 128 + arow) * KDIM + aseg * 16;

    const int wave = tid >> 6;
    const int lane = tid & 63;
    const int wm   = wave & 1;
    const int wn   = wave >> 1;
    const int lrow = lane & 15;
    const int q    = lane >> 4;

    f32x4 acc[4][4] = {};

    #pragma unroll 1
    for (int it = 0; it < 72; ++it) {
        const int tap = it >> 3;
        const int kh  = tap / 3;
        const int kw  = tap - kh * 3;
        const int ci0 = (it & 7) << 5;

        const int iy = yy + kh - 1;
        const int ix = xx + kw - 1;
        const bool valid = ((unsigned)iy < IMG_H) && ((unsigned)ix < IMG_W);

        f32x4 va[4] = {};
        if (valid) {
            const f32x4* src = (const f32x4*)(in +
                ((((size_t)bb * IMG_H + iy) * IMG_W + ix) * CIN + ci0 + aseg * 16));
            va[0] = src[0]; va[1] = src[1]; va[2] = src[2]; va[3] = src[3];
        }
        const uint4 wb0 = *(const uint4*)(wt_row + it * 32);
        const uint4 wb1 = *(const uint4*)(wt_row + it * 32 + 8);

        __syncthreads();

        bf16x8 pa0, pa1;
        #pragma unroll
        for (int e = 0; e < 8; ++e) pa0[e] = (bf16_t)va[e >> 2][e & 3];
        #pragma unroll
        for (int e = 0; e < 8; ++e) pa1[e] = (bf16_t)va[2 + (e >> 2)][e & 3];
        *(bf16x8*)(&Alf[arow * ASTR + aseg * 16])     = pa0;
        *(bf16x8*)(&Alf[arow * ASTR + aseg * 16 + 8]) = pa1;
        *(uint4*)(&Blf[arow * BSTR + aseg * 16])      = wb0;
        *(uint4*)(&Blf[arow * BSTR + aseg * 16 + 8])  = wb1;

        __syncthreads();

        bf16x8 af[4], bf[4];
        #pragma unroll
        for (int i = 0; i < 4; ++i)
            af[i] = *(const bf16x8*)(&Alf[(wm * 64 + i * 16 + lrow) * ASTR + q * 8]);
        #pragma unroll
        for (int j = 0; j < 4; ++j)
            bf[j] = *(const bf16x8*)(&Blf[(wn * 64 + j * 16 + lrow) * BSTR + q * 8]);

        #pragma unroll
        for (int i = 0; i < 4; ++i)
            #pragma unroll
            for (int j = 0; j < 4; ++j)
                acc[i][j] = __builtin_amdgcn_mfma_f32_16x16x32_bf16(af[i], bf[j], acc[i][j], 0, 0, 0);
    }

    const int co_base = ntile * 128 + wn * 64;
    float bv[4];
    #pragma unroll
    for (int j = 0; j < 4; ++j) bv[j] = bias[co_base + j * 16 + lrow];

    const int mrow_base = mtile * 128 + wm * 64;
    #pragma unroll
    for (int i = 0; i < 4; ++i) {
        #pragma unroll
        for (int rr = 0; rr < 4; ++rr) {
            const int mm = mrow_base + i * 16 + q * 4 + rr;
            float* op = out + (size_t)mm * COUT + co_base;
            #pragma unroll
            for (int j = 0; j < 4; ++j)
                op[j * 16 + lrow] = acc[i][j][rr] + bv[j];
        }
    }
}

extern "C" void kernel_launch(void* const* d_in, const int* in_sizes, int n_in,
                              void* d_out, int out_size, void* d_ws, size_t ws_size,
                              hipStream_t stream) {
    const float* inputs = (const float*)d_in[0];
    const float* kernel = (const float*)d_in[1];
    const float* bias   = (const float*)d_in[2];
    float*       outp   = (float*)d_out;

    const size_t p_elems = (size_t)IMG_B * PHW * CIN;               // 27,557,888
    const size_t p_bytes = p_elems * sizeof(bf16_t);                // 55.1 MB
    const size_t w_bytes = (size_t)KDIM * COUT * sizeof(bf16_t);    // 1.18 MB

    if (ws_size >= p_bytes + w_bytes) {
        bf16_t* pimg = (bf16_t*)d_ws;
        bf16_t* wt   = (bf16_t*)((char*)d_ws + p_bytes);
        prep_weights<<<WT_BLOCKS, 256, 0, stream>>>(kernel, wt);
        prep_border<<<BORDER_BLOCKS, 256, 0, stream>>>(pimg);
        prep_interior<<<INT_BLOCKS, 256, 0, stream>>>(inputs, pimg);
        conv_mfma_p<<<(M_TOT / 128) * 2, 256, 0, stream>>>(pimg, wt, bias, outp);
    } else {
        bf16_t* wt = (bf16_t*)d_ws;
        prep_weights<<<WT_BLOCKS, 256, 0, stream>>>(kernel, wt);
        conv_mfma<<<(M_TOT / 128) * 2, 256, 0, stream>>>(inputs, wt, bias, outp);
    }
}